// Round 1
// baseline (147.137 us; speedup 1.0000x reference)
//
#include <hip/hip_runtime.h>
#include <stdint.h>

// Problem constants (fixed by reference)
#define NTOK 8192
#define DM   1024
#define NE   8
#define NR   16
#define KX   1152   // DM + NE*NR = 1024 + 128

typedef short bf16x8 __attribute__((ext_vector_type(8)));
typedef float f32x4  __attribute__((ext_vector_type(4)));

__device__ __forceinline__ unsigned short f2bf(float f) {
    union { float f; unsigned u; } v; v.f = f;
    unsigned r = v.u + 0x7fffu + ((v.u >> 16) & 1u);   // RNE
    return (unsigned short)(r >> 16);
}

__device__ __forceinline__ void gld16(const void* g, void* l) {
    __builtin_amdgcn_global_load_lds((__attribute__((address_space(1))) void*)g,
                                     (__attribute__((address_space(3))) void*)l,
                                     16, 0, 0);
}

// ---------------------------------------------------------------------------
// K2: build WBext[1024][1152] bf16 = [W_base[j][d] | B[e][r][j]] and
//     At[128][1024] bf16 = Aflat^T (At[p][d] = A[e][d][r], p = e*16+r)
// ---------------------------------------------------------------------------
__global__ __launch_bounds__(256) void cvt_w(const float* __restrict__ Wb,
                                             const float* __restrict__ Bsrc,
                                             const float* __restrict__ Asrc,
                                             unsigned short* __restrict__ WBext,
                                             unsigned short* __restrict__ At) {
    const int j = blockIdx.x;        // 0..1023 (output column of main GEMM)
    const int t = threadIdx.x;
    unsigned short* row = WBext + (size_t)j * KX;
    for (int c = t; c < DM; c += 256) row[c] = f2bf(Wb[j * DM + c]);
    if (t < 128) {
        // Bflat[p][j] = Bsrc[p*1024 + j]  (B is [E,R,D] contiguous)
        row[DM + t] = f2bf(Bsrc[(size_t)t * DM + j]);
    }
    if (j < 128) {
        const int e = j >> 4, r = j & 15;
        for (int d = t; d < DM; d += 256)
            At[(size_t)j * DM + d] = f2bf(Asrc[e * (DM * NR) + d * NR + r]);
    }
}

// ---------------------------------------------------------------------------
// K1: fp32 gating (wave per token) + x -> bf16 into Xext[:, 0:1024]
// ---------------------------------------------------------------------------
__global__ __launch_bounds__(256) void gate_cvt(const float* __restrict__ x,
                                                const float* __restrict__ Wg,
                                                float* __restrict__ combine,
                                                unsigned short* __restrict__ Xext) {
    const int t = threadIdx.x;
    const int lane = t & 63;
    const int w = t >> 6;
    const int n = blockIdx.x * 4 + w;      // grid 2048 * 4 waves = 8192 tokens

    const float4* x4 = (const float4*)(x + (size_t)n * DM);
    float4 xv[4];
    #pragma unroll
    for (int i = 0; i < 4; ++i) xv[i] = x4[i * 64 + lane];

    float acc[NE];
    #pragma unroll
    for (int e = 0; e < NE; ++e) {
        const float4* wg4 = (const float4*)(Wg + (size_t)e * DM);
        float s = 0.f;
        #pragma unroll
        for (int i = 0; i < 4; ++i) {
            float4 g = wg4[i * 64 + lane];
            s += xv[i].x * g.x + xv[i].y * g.y + xv[i].z * g.z + xv[i].w * g.w;
        }
        acc[e] = s;
    }
    // full-wave butterfly reduce (all lanes end with the 8 logits)
    #pragma unroll
    for (int off = 32; off >= 1; off >>= 1) {
        #pragma unroll
        for (int e = 0; e < NE; ++e) acc[e] += __shfl_xor(acc[e], off, 64);
    }
    // top-2 (strict > keeps lowest index on ties, matching lax.top_k)
    float best = acc[0]; int bi = 0;
    #pragma unroll
    for (int e = 1; e < NE; ++e) if (acc[e] > best) { best = acc[e]; bi = e; }
    float sec = -1e30f; int si = 0;
    #pragma unroll
    for (int e = 0; e < NE; ++e) if (e != bi && acc[e] > sec) { sec = acc[e]; si = e; }
    const float ed = __expf(sec - best);
    const float w0 = 1.f / (1.f + ed);
    const float w1 = ed * w0;
    if (lane < NE)
        combine[n * NE + lane] = (lane == bi) ? w0 : ((lane == si) ? w1 : 0.f);

    // x -> bf16 (coalesced ushort4 stores)
    unsigned short* xrow = Xext + (size_t)n * KX;
    #pragma unroll
    for (int i = 0; i < 4; ++i) {
        ushort4 b;
        b.x = f2bf(xv[i].x); b.y = f2bf(xv[i].y);
        b.z = f2bf(xv[i].z); b.w = f2bf(xv[i].w);
        *(ushort4*)(xrow + (i * 64 + lane) * 4) = b;
    }
}

// ---------------------------------------------------------------------------
// K3: Hfull = (x_bf16 @ At^T) * combine  -> bf16 into Xext[:, 1024:1152]
//     tile 32 tokens x 128 cols, BK=64, 4 waves (wave = 32-col group)
// ---------------------------------------------------------------------------
__global__ __launch_bounds__(256) void hall_kernel(unsigned short* Xext,
                                                   const unsigned short* __restrict__ At,
                                                   const float* __restrict__ combine) {
    __shared__ __align__(16) unsigned short lds[(32 + 128) * 64];  // A:4KB  B:16KB
    const int t = threadIdx.x;
    const int lane = t & 63;
    const int w = t >> 6;
    const int quad = lane >> 4;
    const int l15 = lane & 15;
    const int bm = blockIdx.x;   // 256 blocks * 32 tokens

    f32x4 acc[2][2] = {};
    const unsigned short* gA = Xext + (size_t)(bm * 32 + (t >> 3)) * KX + (t & 7) * 8;

    for (int k0 = 0; k0 < DM; k0 += 64) {
        __syncthreads();
        gld16(gA + k0, (char*)lds + w * 1024);                     // A tile 32x64
        #pragma unroll
        for (int r = 0; r < 4; ++r) {                              // B tile 128x64
            const unsigned short* g = At + (size_t)(r * 32 + (t >> 3)) * DM + k0 + (t & 7) * 8;
            gld16(g, (char*)lds + 4096 + r * 4096 + w * 1024);
        }
        __syncthreads();
        #pragma unroll
        for (int kk = 0; kk < 2; ++kk) {
            bf16x8 a[2], b[2];
            #pragma unroll
            for (int i = 0; i < 2; ++i)
                a[i] = *(const bf16x8*)&lds[(i * 16 + l15) * 64 + kk * 32 + quad * 8];
            #pragma unroll
            for (int jf = 0; jf < 2; ++jf)
                b[jf] = *(const bf16x8*)&lds[2048 + (w * 32 + jf * 16 + l15) * 64 + kk * 32 + quad * 8];
            #pragma unroll
            for (int i = 0; i < 2; ++i)
                #pragma unroll
                for (int jf = 0; jf < 2; ++jf)
                    acc[i][jf] = __builtin_amdgcn_mfma_f32_16x16x32_bf16(a[i], b[jf], acc[i][jf], 0, 0, 0);
        }
    }
    #pragma unroll
    for (int i = 0; i < 2; ++i)
        #pragma unroll
        for (int jf = 0; jf < 2; ++jf) {
            const int p = w * 32 + jf * 16 + l15;
            const int e = p >> 4;
            #pragma unroll
            for (int v = 0; v < 4; ++v) {
                const int n = bm * 32 + i * 16 + quad * 4 + v;
                const float val = acc[i][jf][v] * combine[n * NE + e];
                Xext[(size_t)n * KX + DM + p] = f2bf(val);
            }
        }
}

// ---------------------------------------------------------------------------
// K4: out[8192][1024] = Xext[8192][1152] @ WBext[1024][1152]^T + bias
//     m97 structure: 128x128 tile, BK=32, global_load_lds w16, 16 MFMA/iter
// ---------------------------------------------------------------------------
__global__ __launch_bounds__(256) void mgemm(const unsigned short* __restrict__ Xext,
                                             const unsigned short* __restrict__ WBext,
                                             const float* __restrict__ bias,
                                             float* __restrict__ out) {
    __shared__ __align__(16) unsigned short lds[8192];   // A 8KB | B 8KB
    const int t = threadIdx.x;
    const int lane = t & 63;
    const int w = t >> 6;
    const int quad = lane >> 4;
    const int l15 = lane & 15;
    const int bm = blockIdx.x;   // 64
    const int bn = blockIdx.y;   // 8
    const int wm = (w & 1) * 64;
    const int wn = (w >> 1) * 64;

    f32x4 acc[4][4] = {};

    const unsigned short* gA0 = Xext  + (size_t)(bm * 128 +      (t >> 2)) * KX + (t & 3) * 8;
    const unsigned short* gA1 = Xext  + (size_t)(bm * 128 + 64 + (t >> 2)) * KX + (t & 3) * 8;
    const unsigned short* gB0 = WBext + (size_t)(bn * 128 +      (t >> 2)) * KX + (t & 3) * 8;
    const unsigned short* gB1 = WBext + (size_t)(bn * 128 + 64 + (t >> 2)) * KX + (t & 3) * 8;

    for (int k0 = 0; k0 < KX; k0 += 32) {
        __syncthreads();
        gld16(gA0 + k0, (char*)lds +           w * 1024);
        gld16(gA1 + k0, (char*)lds +  4096 +   w * 1024);
        gld16(gB0 + k0, (char*)lds +  8192 +   w * 1024);
        gld16(gB1 + k0, (char*)lds + 12288 +   w * 1024);
        __syncthreads();
        bf16x8 a[4], b[4];
        #pragma unroll
        for (int i = 0; i < 4; ++i)
            a[i] = *(const bf16x8*)&lds[(wm + i * 16 + l15) * 32 + quad * 8];
        #pragma unroll
        for (int j = 0; j < 4; ++j)
            b[j] = *(const bf16x8*)&lds[4096 + (wn + j * 16 + l15) * 32 + quad * 8];
        #pragma unroll
        for (int i = 0; i < 4; ++i)
            #pragma unroll
            for (int j = 0; j < 4; ++j)
                acc[i][j] = __builtin_amdgcn_mfma_f32_16x16x32_bf16(a[i], b[j], acc[i][j], 0, 0, 0);
    }

    #pragma unroll
    for (int j = 0; j < 4; ++j) {
        const int col = bn * 128 + wn + j * 16 + l15;
        const float bv = bias[col];
        #pragma unroll
        for (int i = 0; i < 4; ++i) {
            const int row = bm * 128 + wm + i * 16 + quad * 4;
            #pragma unroll
            for (int v = 0; v < 4; ++v)
                out[(size_t)(row + v) * DM + col] = acc[i][j][v] + bv;
        }
    }
}

// ---------------------------------------------------------------------------
extern "C" void kernel_launch(void* const* d_in, const int* in_sizes, int n_in,
                              void* d_out, int out_size, void* d_ws, size_t ws_size,
                              hipStream_t stream) {
    const float* x  = (const float*)d_in[0];   // [8192,1024]
    const float* Wg = (const float*)d_in[1];   // [8,1024]
    const float* A  = (const float*)d_in[2];   // [8,1024,16]
    const float* B  = (const float*)d_in[3];   // [8,16,1024]
    const float* Wb = (const float*)d_in[4];   // [1024,1024]
    const float* bb = (const float*)d_in[5];   // [1024]
    float* out = (float*)d_out;

    // workspace carve (20.75 MB total)
    char* ws = (char*)d_ws;
    float*          combine = (float*)ws;                                   // 262144 B
    unsigned short* Xext    = (unsigned short*)(ws + 262144);               // 18874368 B
    unsigned short* WBext   = (unsigned short*)(ws + 262144 + 18874368);    // 2359296 B
    unsigned short* At      = (unsigned short*)(ws + 262144 + 18874368 + 2359296); // 262144 B

    hipLaunchKernelGGL(cvt_w,       dim3(1024),  dim3(256), 0, stream, Wb, B, A, WBext, At);
    hipLaunchKernelGGL(gate_cvt,    dim3(2048),  dim3(256), 0, stream, x, Wg, combine, Xext);
    hipLaunchKernelGGL(hall_kernel, dim3(256),   dim3(256), 0, stream, Xext, At, combine);
    hipLaunchKernelGGL(mgemm,       dim3(64, 8), dim3(256), 0, stream, Xext, WBext, bb, out);
}

// Round 2
// 142.758 us; speedup vs baseline: 1.0307x; 1.0307x over previous
//
#include <hip/hip_runtime.h>
#include <stdint.h>

// Problem constants (fixed by reference)
#define NTOK 8192
#define DM   1024
#define NE   8
#define NR   16
#define KX   1152   // DM + NE*NR = 1024 + 128

typedef short bf16x8 __attribute__((ext_vector_type(8)));
typedef float f32x4  __attribute__((ext_vector_type(4)));

__device__ __forceinline__ unsigned short f2bf(float f) {
    union { float f; unsigned u; } v; v.f = f;
    unsigned r = v.u + 0x7fffu + ((v.u >> 16) & 1u);   // RNE
    return (unsigned short)(r >> 16);
}

__device__ __forceinline__ void gld16(const void* g, void* l) {
    __builtin_amdgcn_global_load_lds((__attribute__((address_space(1))) void*)g,
                                     (__attribute__((address_space(3))) void*)l,
                                     16, 0, 0);
}

// ---------------------------------------------------------------------------
// prep: fused role-by-block kernel.
//  blocks [0,2048):     fp32 gating (wave/token) + x -> bf16 into Xext[:,0:1024]
//  blocks [2048,3072):  WBext[j][0:1152] = [W_base[j][:] | B[:, j]]  (bf16)
//  blocks [3072,3200):  At[p][0:1024] = A[e][: ][r] transpose       (bf16)
// ---------------------------------------------------------------------------
__global__ __launch_bounds__(256) void prep(const float* __restrict__ x,
                                            const float* __restrict__ Wg,
                                            const float* __restrict__ Asrc,
                                            const float* __restrict__ Bsrc,
                                            const float* __restrict__ Wb,
                                            float* __restrict__ combine,
                                            unsigned short* __restrict__ Xext,
                                            unsigned short* __restrict__ WBext,
                                            unsigned short* __restrict__ At) {
    const int b = blockIdx.x;
    const int t = threadIdx.x;

    if (b < 2048) {
        // ---- gating + x conversion ----
        const int lane = t & 63;
        const int w = t >> 6;
        const int n = b * 4 + w;

        const float4* x4 = (const float4*)(x + (size_t)n * DM);
        float4 xv[4];
        #pragma unroll
        for (int i = 0; i < 4; ++i) xv[i] = x4[i * 64 + lane];

        float acc[NE];
        #pragma unroll
        for (int e = 0; e < NE; ++e) {
            const float4* wg4 = (const float4*)(Wg + (size_t)e * DM);
            float s = 0.f;
            #pragma unroll
            for (int i = 0; i < 4; ++i) {
                float4 g = wg4[i * 64 + lane];
                s += xv[i].x * g.x + xv[i].y * g.y + xv[i].z * g.z + xv[i].w * g.w;
            }
            acc[e] = s;
        }
        #pragma unroll
        for (int off = 32; off >= 1; off >>= 1) {
            #pragma unroll
            for (int e = 0; e < NE; ++e) acc[e] += __shfl_xor(acc[e], off, 64);
        }
        // top-2, lowest index wins ties (matches lax.top_k)
        float best = acc[0]; int bi = 0;
        #pragma unroll
        for (int e = 1; e < NE; ++e) if (acc[e] > best) { best = acc[e]; bi = e; }
        float sec = -1e30f; int si = 0;
        #pragma unroll
        for (int e = 0; e < NE; ++e) if (e != bi && acc[e] > sec) { sec = acc[e]; si = e; }
        const float ed = __expf(sec - best);
        const float w0 = 1.f / (1.f + ed);
        const float w1 = ed * w0;
        if (lane < NE)
            combine[n * NE + lane] = (lane == bi) ? w0 : ((lane == si) ? w1 : 0.f);

        unsigned short* xrow = Xext + (size_t)n * KX;
        #pragma unroll
        for (int i = 0; i < 4; ++i) {
            ushort4 o;
            o.x = f2bf(xv[i].x); o.y = f2bf(xv[i].y);
            o.z = f2bf(xv[i].z); o.w = f2bf(xv[i].w);
            *(ushort4*)(xrow + (i * 64 + lane) * 4) = o;
        }
    } else if (b < 3072) {
        // ---- WBext row j ----
        const int j = b - 2048;
        unsigned short* row = WBext + (size_t)j * KX;
        float4 v = ((const float4*)(Wb + (size_t)j * DM))[t];
        ushort4 o;
        o.x = f2bf(v.x); o.y = f2bf(v.y); o.z = f2bf(v.z); o.w = f2bf(v.w);
        *(ushort4*)(row + t * 4) = o;
        if (t < 128) row[DM + t] = f2bf(Bsrc[(size_t)t * DM + j]);   // B[e][r][j]
    } else {
        // ---- At row p ----
        const int p = b - 3072;
        const int e = p >> 4, r = p & 15;
        for (int d = t; d < DM; d += 256)
            At[(size_t)p * DM + d] = f2bf(Asrc[e * (DM * NR) + d * NR + r]);
    }
}

// ---------------------------------------------------------------------------
// hall: Hfull = (x_bf16 @ At^T) * combine -> bf16 into Xext[:, 1024:1152]
//       tile 32 tokens x 128 cols, BK=64, 4 waves (wave = 32-col group)
// ---------------------------------------------------------------------------
__global__ __launch_bounds__(256) void hall_kernel(unsigned short* Xext,
                                                   const unsigned short* __restrict__ At,
                                                   const float* __restrict__ combine) {
    __shared__ __align__(16) unsigned short lds[(32 + 128) * 64];  // A:4KB  B:16KB
    const int t = threadIdx.x;
    const int lane = t & 63;
    const int w = t >> 6;
    const int quad = lane >> 4;
    const int l15 = lane & 15;
    const int bm = blockIdx.x;

    f32x4 acc[2][2] = {};
    const unsigned short* gA = Xext + (size_t)(bm * 32 + (t >> 3)) * KX + (t & 7) * 8;

    for (int k0 = 0; k0 < DM; k0 += 64) {
        __syncthreads();
        gld16(gA + k0, (char*)lds + w * 1024);
        #pragma unroll
        for (int r = 0; r < 4; ++r) {
            const unsigned short* g = At + (size_t)(r * 32 + (t >> 3)) * DM + k0 + (t & 7) * 8;
            gld16(g, (char*)lds + 4096 + r * 4096 + w * 1024);
        }
        __syncthreads();
        #pragma unroll
        for (int kk = 0; kk < 2; ++kk) {
            bf16x8 a[2], bb[2];
            #pragma unroll
            for (int i = 0; i < 2; ++i)
                a[i] = *(const bf16x8*)&lds[(i * 16 + l15) * 64 + kk * 32 + quad * 8];
            #pragma unroll
            for (int jf = 0; jf < 2; ++jf)
                bb[jf] = *(const bf16x8*)&lds[2048 + (w * 32 + jf * 16 + l15) * 64 + kk * 32 + quad * 8];
            #pragma unroll
            for (int i = 0; i < 2; ++i)
                #pragma unroll
                for (int jf = 0; jf < 2; ++jf)
                    acc[i][jf] = __builtin_amdgcn_mfma_f32_16x16x32_bf16(a[i], bb[jf], acc[i][jf], 0, 0, 0);
        }
    }
    #pragma unroll
    for (int i = 0; i < 2; ++i)
        #pragma unroll
        for (int jf = 0; jf < 2; ++jf) {
            const int p = w * 32 + jf * 16 + l15;
            const int e = p >> 4;
            #pragma unroll
            for (int v = 0; v < 4; ++v) {
                const int n = bm * 32 + i * 16 + quad * 4 + v;
                const float val = acc[i][jf][v] * combine[n * NE + e];
                Xext[(size_t)n * KX + DM + p] = f2bf(val);
            }
        }
}

// ---------------------------------------------------------------------------
// mgemm: out[8192][1024] = Xext[8192][1152] @ WBext[1024][1152]^T + bias
//   m97 structure: 128x128 tile, BK=32, global_load_lds w16, 16 MFMA/iter.
//   1D grid with XCD-aware decode: XCD x owns bm in [8x, 8x+8) x all bn, so
//   its A rows (2.36 MB) + full B (2.6 MB) are ~L2-resident per XCD.
// ---------------------------------------------------------------------------
__global__ __launch_bounds__(256) void mgemm(const unsigned short* __restrict__ Xext,
                                             const unsigned short* __restrict__ WBext,
                                             const float* __restrict__ bias,
                                             float* __restrict__ out) {
    __shared__ __align__(16) unsigned short lds[8192];   // A 8KB | B 8KB
    const int t = threadIdx.x;
    const int lane = t & 63;
    const int w = t >> 6;
    const int quad = lane >> 4;
    const int l15 = lane & 15;

    const int bid = blockIdx.x;          // 512
    const int xcd = bid & 7;             // round-robin XCD assignment heuristic
    const int loc = bid >> 3;            // 0..63
    const int bm = xcd * 8 + (loc & 7);  // 0..63
    const int bn = loc >> 3;             // 0..7

    const int wm = (w & 1) * 64;
    const int wn = (w >> 1) * 64;

    f32x4 acc[4][4] = {};

    const unsigned short* gA0 = Xext  + (size_t)(bm * 128 +      (t >> 2)) * KX + (t & 3) * 8;
    const unsigned short* gA1 = Xext  + (size_t)(bm * 128 + 64 + (t >> 2)) * KX + (t & 3) * 8;
    const unsigned short* gB0 = WBext + (size_t)(bn * 128 +      (t >> 2)) * KX + (t & 3) * 8;
    const unsigned short* gB1 = WBext + (size_t)(bn * 128 + 64 + (t >> 2)) * KX + (t & 3) * 8;

    for (int k0 = 0; k0 < KX; k0 += 32) {
        __syncthreads();
        gld16(gA0 + k0, (char*)lds +           w * 1024);
        gld16(gA1 + k0, (char*)lds +  4096 +   w * 1024);
        gld16(gB0 + k0, (char*)lds +  8192 +   w * 1024);
        gld16(gB1 + k0, (char*)lds + 12288 +   w * 1024);
        __syncthreads();
        bf16x8 a[4], b[4];
        #pragma unroll
        for (int i = 0; i < 4; ++i)
            a[i] = *(const bf16x8*)&lds[(wm + i * 16 + l15) * 32 + quad * 8];
        #pragma unroll
        for (int j = 0; j < 4; ++j)
            b[j] = *(const bf16x8*)&lds[4096 + (wn + j * 16 + l15) * 32 + quad * 8];
        #pragma unroll
        for (int i = 0; i < 4; ++i)
            #pragma unroll
            for (int j = 0; j < 4; ++j)
                acc[i][j] = __builtin_amdgcn_mfma_f32_16x16x32_bf16(a[i], b[j], acc[i][j], 0, 0, 0);
    }

    #pragma unroll
    for (int j = 0; j < 4; ++j) {
        const int col = bn * 128 + wn + j * 16 + l15;
        const float bv = bias[col];
        #pragma unroll
        for (int i = 0; i < 4; ++i) {
            const int row = bm * 128 + wm + i * 16 + quad * 4;
            #pragma unroll
            for (int v = 0; v < 4; ++v)
                out[(size_t)(row + v) * DM + col] = acc[i][j][v] + bv;
        }
    }
}

// ---------------------------------------------------------------------------
extern "C" void kernel_launch(void* const* d_in, const int* in_sizes, int n_in,
                              void* d_out, int out_size, void* d_ws, size_t ws_size,
                              hipStream_t stream) {
    const float* x  = (const float*)d_in[0];   // [8192,1024]
    const float* Wg = (const float*)d_in[1];   // [8,1024]
    const float* A  = (const float*)d_in[2];   // [8,1024,16]
    const float* B  = (const float*)d_in[3];   // [8,16,1024]
    const float* Wb = (const float*)d_in[4];   // [1024,1024]
    const float* bb = (const float*)d_in[5];   // [1024]
    float* out = (float*)d_out;

    // workspace carve (20.75 MB total)
    char* ws = (char*)d_ws;
    float*          combine = (float*)ws;                                   // 262144 B
    unsigned short* Xext    = (unsigned short*)(ws + 262144);               // 18874368 B
    unsigned short* WBext   = (unsigned short*)(ws + 262144 + 18874368);    // 2359296 B
    unsigned short* At      = (unsigned short*)(ws + 262144 + 18874368 + 2359296); // 262144 B

    hipLaunchKernelGGL(prep,        dim3(3200), dim3(256), 0, stream,
                       x, Wg, A, B, Wb, combine, Xext, WBext, At);
    hipLaunchKernelGGL(hall_kernel, dim3(256),  dim3(256), 0, stream, Xext, At, combine);
    hipLaunchKernelGGL(mgemm,       dim3(512),  dim3(256), 0, stream, Xext, WBext, bb, out);
}

// Round 3
// 136.905 us; speedup vs baseline: 1.0747x; 1.0427x over previous
//
#include <hip/hip_runtime.h>
#include <stdint.h>

// Problem constants (fixed by reference)
#define NTOK 8192
#define DM   1024
#define NE   8
#define NR   16
#define KX   1152   // DM + NE*NR = 1024 + 128

typedef short bf16x8 __attribute__((ext_vector_type(8)));
typedef float f32x4  __attribute__((ext_vector_type(4)));

__device__ __forceinline__ unsigned short f2bf(float f) {
    union { float f; unsigned u; } v; v.f = f;
    unsigned r = v.u + 0x7fffu + ((v.u >> 16) & 1u);   // RNE
    return (unsigned short)(r >> 16);
}

__device__ __forceinline__ void gld16(const void* g, void* l) {
    __builtin_amdgcn_global_load_lds((__attribute__((address_space(1))) void*)g,
                                     (__attribute__((address_space(3))) void*)l,
                                     16, 0, 0);
}

// ---------------------------------------------------------------------------
// prep: fused role-by-block kernel.
//  blocks [0,2048):     fp32 gating (wave/token) + x -> bf16 into Xext[:,0:1024]
//  blocks [2048,3072):  WBext[j][0:1152] = [W_base[j][:] | B[:, j]]  (bf16)
//  blocks [3072,3200):  At[p][0:1024] = A[e][:][r] transpose        (bf16)
// ---------------------------------------------------------------------------
__global__ __launch_bounds__(256) void prep(const float* __restrict__ x,
                                            const float* __restrict__ Wg,
                                            const float* __restrict__ Asrc,
                                            const float* __restrict__ Bsrc,
                                            const float* __restrict__ Wb,
                                            float* __restrict__ combine,
                                            unsigned short* __restrict__ Xext,
                                            unsigned short* __restrict__ WBext,
                                            unsigned short* __restrict__ At) {
    const int b = blockIdx.x;
    const int t = threadIdx.x;

    if (b < 2048) {
        const int lane = t & 63;
        const int w = t >> 6;
        const int n = b * 4 + w;

        const float4* x4 = (const float4*)(x + (size_t)n * DM);
        float4 xv[4];
        #pragma unroll
        for (int i = 0; i < 4; ++i) xv[i] = x4[i * 64 + lane];

        float acc[NE];
        #pragma unroll
        for (int e = 0; e < NE; ++e) {
            const float4* wg4 = (const float4*)(Wg + (size_t)e * DM);
            float s = 0.f;
            #pragma unroll
            for (int i = 0; i < 4; ++i) {
                float4 g = wg4[i * 64 + lane];
                s += xv[i].x * g.x + xv[i].y * g.y + xv[i].z * g.z + xv[i].w * g.w;
            }
            acc[e] = s;
        }
        #pragma unroll
        for (int off = 32; off >= 1; off >>= 1) {
            #pragma unroll
            for (int e = 0; e < NE; ++e) acc[e] += __shfl_xor(acc[e], off, 64);
        }
        // top-2, lowest index wins ties (matches lax.top_k)
        float best = acc[0]; int bi = 0;
        #pragma unroll
        for (int e = 1; e < NE; ++e) if (acc[e] > best) { best = acc[e]; bi = e; }
        float sec = -1e30f; int si = 0;
        #pragma unroll
        for (int e = 0; e < NE; ++e) if (e != bi && acc[e] > sec) { sec = acc[e]; si = e; }
        const float ed = __expf(sec - best);
        const float w0 = 1.f / (1.f + ed);
        const float w1 = ed * w0;
        if (lane < NE)
            combine[n * NE + lane] = (lane == bi) ? w0 : ((lane == si) ? w1 : 0.f);

        unsigned short* xrow = Xext + (size_t)n * KX;
        #pragma unroll
        for (int i = 0; i < 4; ++i) {
            ushort4 o;
            o.x = f2bf(xv[i].x); o.y = f2bf(xv[i].y);
            o.z = f2bf(xv[i].z); o.w = f2bf(xv[i].w);
            *(ushort4*)(xrow + (i * 64 + lane) * 4) = o;
        }
    } else if (b < 3072) {
        const int j = b - 2048;
        unsigned short* row = WBext + (size_t)j * KX;
        float4 v = ((const float4*)(Wb + (size_t)j * DM))[t];
        ushort4 o;
        o.x = f2bf(v.x); o.y = f2bf(v.y); o.z = f2bf(v.z); o.w = f2bf(v.w);
        *(ushort4*)(row + t * 4) = o;
        if (t < 128) row[DM + t] = f2bf(Bsrc[(size_t)t * DM + j]);   // B[e][r][j]
    } else {
        const int p = b - 3072;
        const int e = p >> 4, r = p & 15;
        for (int d = t; d < DM; d += 256)
            At[(size_t)p * DM + d] = f2bf(Asrc[e * (DM * NR) + d * NR + r]);
    }
}

// ---------------------------------------------------------------------------
// hall: Hfull = (x_bf16 @ At^T) * combine -> bf16 into Xext[:, 1024:1152]
//   tile 32 tokens x 128 cols, BK=64. XOR-swizzled LDS K-segments:
//   lane stages global seg (t&7)^(row&7) at LDS pos (t&7); reader fetches
//   global seg gs at LDS pos gs^(row&7) -> 2-way banks (free, m136).
// ---------------------------------------------------------------------------
__global__ __launch_bounds__(256) void hall_kernel(unsigned short* Xext,
                                                   const unsigned short* __restrict__ At,
                                                   const float* __restrict__ combine) {
    __shared__ __align__(16) unsigned short lds[(32 + 128) * 64];  // A:4KB  B:16KB
    const int t = threadIdx.x;
    const int lane = t & 63;
    const int w = t >> 6;
    const int quad = lane >> 4;
    const int l15 = lane & 15;
    const int bm = blockIdx.x;

    const int srow = t >> 3;                     // 0..31
    const int seg  = (t & 7) ^ (srow & 7);       // XOR swizzle (global side)

    f32x4 acc[2][2] = {};
    const unsigned short* gA = Xext + (size_t)(bm * 32 + srow) * KX + seg * 8;

    for (int k0 = 0; k0 < DM; k0 += 64) {
        __syncthreads();
        gld16(gA + k0, (char*)lds + w * 1024);
        #pragma unroll
        for (int r = 0; r < 4; ++r) {
            const unsigned short* g = At + (size_t)(r * 32 + srow) * DM + k0 + seg * 8;
            gld16(g, (char*)lds + 4096 + r * 4096 + w * 1024);
        }
        __syncthreads();
        #pragma unroll
        for (int kk = 0; kk < 2; ++kk) {
            const int gs = kk * 4 + quad;
            const int sw = (gs ^ (l15 & 7)) * 8;
            bf16x8 a[2], bb[2];
            #pragma unroll
            for (int i = 0; i < 2; ++i)
                a[i] = *(const bf16x8*)&lds[(i * 16 + l15) * 64 + sw];
            #pragma unroll
            for (int jf = 0; jf < 2; ++jf)
                bb[jf] = *(const bf16x8*)&lds[2048 + (w * 32 + jf * 16 + l15) * 64 + sw];
            #pragma unroll
            for (int i = 0; i < 2; ++i)
                #pragma unroll
                for (int jf = 0; jf < 2; ++jf)
                    acc[i][jf] = __builtin_amdgcn_mfma_f32_16x16x32_bf16(a[i], bb[jf], acc[i][jf], 0, 0, 0);
        }
    }
    #pragma unroll
    for (int i = 0; i < 2; ++i)
        #pragma unroll
        for (int jf = 0; jf < 2; ++jf) {
            const int p = w * 32 + jf * 16 + l15;
            const int e = p >> 4;
            #pragma unroll
            for (int v = 0; v < 4; ++v) {
                const int n = bm * 32 + i * 16 + quad * 4 + v;
                const float val = acc[i][jf][v] * combine[n * NE + e];
                Xext[(size_t)n * KX + DM + p] = f2bf(val);
            }
        }
}

// ---------------------------------------------------------------------------
// mgemm: out[8192][1024] = Xext[8192][1152] @ WBext[1024][1152]^T + bias
//   128x128 tile, BK=64 (half the barrier drains of BK=32), 32 KB LDS,
//   XOR-swizzled K-segments (conflict-free ds_read_b128),
//   global_load_lds w16, XCD-aware block decode.
// ---------------------------------------------------------------------------
__global__ __launch_bounds__(256) void mgemm(const unsigned short* __restrict__ Xext,
                                             const unsigned short* __restrict__ WBext,
                                             const float* __restrict__ bias,
                                             float* __restrict__ out) {
    __shared__ __align__(16) unsigned short lds[16384];   // A 16KB | B 16KB
    const int t = threadIdx.x;
    const int lane = t & 63;
    const int w = t >> 6;
    const int quad = lane >> 4;
    const int l15 = lane & 15;

    const int bid = blockIdx.x;          // 512
    const int xcd = bid & 7;             // XCD x owns bm in [8x,8x+8) x all bn
    const int loc = bid >> 3;
    const int bm = xcd * 8 + (loc & 7);  // 0..63
    const int bn = loc >> 3;             // 0..7

    const int wm = (w & 1) * 64;
    const int wn = (w >> 1) * 64;

    f32x4 acc[4][4] = {};

    const int srow = t >> 3;                     // staging row within 32-row chunk
    const int seg  = (t & 7) ^ (srow & 7);       // XOR swizzle (global side)
    const unsigned short* gA = Xext  + (size_t)(bm * 128 + srow) * KX + seg * 8;
    const unsigned short* gB = WBext + (size_t)(bn * 128 + srow) * KX + seg * 8;
    char* ldsA = (char*)lds + w * 1024;          // + lane*16 applied by HW
    char* ldsB = (char*)lds + 16384 + w * 1024;

    for (int k0 = 0; k0 < KX; k0 += 64) {        // 18 iterations
        __syncthreads();
        #pragma unroll
        for (int c = 0; c < 4; ++c) {
            gld16(gA + (size_t)c * 32 * KX + k0, ldsA + c * 4096);
            gld16(gB + (size_t)c * 32 * KX + k0, ldsB + c * 4096);
        }
        __syncthreads();
        #pragma unroll
        for (int kk = 0; kk < 2; ++kk) {
            const int gs = kk * 4 + quad;
            const int sw = (gs ^ (l15 & 7)) * 8;
            bf16x8 a[4], b[4];
            #pragma unroll
            for (int i = 0; i < 4; ++i)
                a[i] = *(const bf16x8*)&lds[(wm + i * 16 + l15) * 64 + sw];
            #pragma unroll
            for (int j = 0; j < 4; ++j)
                b[j] = *(const bf16x8*)&lds[8192 + (wn + j * 16 + l15) * 64 + sw];
            #pragma unroll
            for (int i = 0; i < 4; ++i)
                #pragma unroll
                for (int j = 0; j < 4; ++j)
                    acc[i][j] = __builtin_amdgcn_mfma_f32_16x16x32_bf16(a[i], b[j], acc[i][j], 0, 0, 0);
        }
    }

    #pragma unroll
    for (int j = 0; j < 4; ++j) {
        const int col = bn * 128 + wn + j * 16 + l15;
        const float bv = bias[col];
        #pragma unroll
        for (int i = 0; i < 4; ++i) {
            const int row = bm * 128 + wm + i * 16 + quad * 4;
            #pragma unroll
            for (int v = 0; v < 4; ++v)
                out[(size_t)(row + v) * DM + col] = acc[i][j][v] + bv;
        }
    }
}

// ---------------------------------------------------------------------------
extern "C" void kernel_launch(void* const* d_in, const int* in_sizes, int n_in,
                              void* d_out, int out_size, void* d_ws, size_t ws_size,
                              hipStream_t stream) {
    const float* x  = (const float*)d_in[0];   // [8192,1024]
    const float* Wg = (const float*)d_in[1];   // [8,1024]
    const float* A  = (const float*)d_in[2];   // [8,1024,16]
    const float* B  = (const float*)d_in[3];   // [8,16,1024]
    const float* Wb = (const float*)d_in[4];   // [1024,1024]
    const float* bb = (const float*)d_in[5];   // [1024]
    float* out = (float*)d_out;

    char* ws = (char*)d_ws;
    float*          combine = (float*)ws;                                   // 262144 B
    unsigned short* Xext    = (unsigned short*)(ws + 262144);               // 18874368 B
    unsigned short* WBext   = (unsigned short*)(ws + 262144 + 18874368);    // 2359296 B
    unsigned short* At      = (unsigned short*)(ws + 262144 + 18874368 + 2359296); // 262144 B

    hipLaunchKernelGGL(prep,        dim3(3200), dim3(256), 0, stream,
                       x, Wg, A, B, Wb, combine, Xext, WBext, At);
    hipLaunchKernelGGL(hall_kernel, dim3(256),  dim3(256), 0, stream, Xext, At, combine);
    hipLaunchKernelGGL(mgemm,       dim3(512),  dim3(256), 0, stream, Xext, WBext, bb, out);
}

// Round 5
// 134.858 us; speedup vs baseline: 1.0910x; 1.0152x over previous
//
#include <hip/hip_runtime.h>
#include <stdint.h>

// Problem constants (fixed by reference)
#define NTOK 8192
#define DM   1024
#define NE   8
#define NR   16
#define KX   1152   // DM + NE*NR = 1024 + 128

typedef short bf16x8 __attribute__((ext_vector_type(8)));
typedef float f32x4  __attribute__((ext_vector_type(4)));

__device__ __forceinline__ unsigned short f2bf(float f) {
    union { float f; unsigned u; } v; v.f = f;
    unsigned r = v.u + 0x7fffu + ((v.u >> 16) & 1u);   // RNE
    return (unsigned short)(r >> 16);
}

__device__ __forceinline__ void gld16(const void* g, void* l) {
    __builtin_amdgcn_global_load_lds((__attribute__((address_space(1))) void*)g,
                                     (__attribute__((address_space(3))) void*)l,
                                     16, 0, 0);
}

// ---------------------------------------------------------------------------
// prep: fused role-by-block kernel.
//  blocks [0,2048):     fp32 gating (wave/token) + x -> bf16 into Xext[:,0:1024]
//  blocks [2048,3072):  WBext[j][0:1152] = [W_base[j][:] | B[:, j]]  (bf16)
//  blocks [3072,3200):  At[p][0:1024] = A[e][:][r] transpose        (bf16)
// ---------------------------------------------------------------------------
__global__ __launch_bounds__(256) void prep(const float* __restrict__ x,
                                            const float* __restrict__ Wg,
                                            const float* __restrict__ Asrc,
                                            const float* __restrict__ Bsrc,
                                            const float* __restrict__ Wb,
                                            float* __restrict__ combine,
                                            unsigned short* __restrict__ Xext,
                                            unsigned short* __restrict__ WBext,
                                            unsigned short* __restrict__ At) {
    const int b = blockIdx.x;
    const int t = threadIdx.x;

    if (b < 2048) {
        const int lane = t & 63;
        const int w = t >> 6;
        const int n = b * 4 + w;

        const float4* x4 = (const float4*)(x + (size_t)n * DM);
        float4 xv[4];
        #pragma unroll
        for (int i = 0; i < 4; ++i) xv[i] = x4[i * 64 + lane];

        float acc[NE];
        #pragma unroll
        for (int e = 0; e < NE; ++e) {
            const float4* wg4 = (const float4*)(Wg + (size_t)e * DM);
            float s = 0.f;
            #pragma unroll
            for (int i = 0; i < 4; ++i) {
                float4 g = wg4[i * 64 + lane];
                s += xv[i].x * g.x + xv[i].y * g.y + xv[i].z * g.z + xv[i].w * g.w;
            }
            acc[e] = s;
        }
        #pragma unroll
        for (int off = 32; off >= 1; off >>= 1) {
            #pragma unroll
            for (int e = 0; e < NE; ++e) acc[e] += __shfl_xor(acc[e], off, 64);
        }
        // top-2, lowest index wins ties (matches lax.top_k)
        float best = acc[0]; int bi = 0;
        #pragma unroll
        for (int e = 1; e < NE; ++e) if (acc[e] > best) { best = acc[e]; bi = e; }
        float sec = -1e30f; int si = 0;
        #pragma unroll
        for (int e = 0; e < NE; ++e) if (e != bi && acc[e] > sec) { sec = acc[e]; si = e; }
        const float ed = __expf(sec - best);
        const float w0 = 1.f / (1.f + ed);
        const float w1 = ed * w0;
        if (lane < NE)
            combine[n * NE + lane] = (lane == bi) ? w0 : ((lane == si) ? w1 : 0.f);

        unsigned short* xrow = Xext + (size_t)n * KX;
        #pragma unroll
        for (int i = 0; i < 4; ++i) {
            ushort4 o;
            o.x = f2bf(xv[i].x); o.y = f2bf(xv[i].y);
            o.z = f2bf(xv[i].z); o.w = f2bf(xv[i].w);
            *(ushort4*)(xrow + (i * 64 + lane) * 4) = o;
        }
    } else if (b < 3072) {
        const int j = b - 2048;
        unsigned short* row = WBext + (size_t)j * KX;
        float4 v = ((const float4*)(Wb + (size_t)j * DM))[t];
        ushort4 o;
        o.x = f2bf(v.x); o.y = f2bf(v.y); o.z = f2bf(v.z); o.w = f2bf(v.w);
        *(ushort4*)(row + t * 4) = o;
        if (t < 128) row[DM + t] = f2bf(Bsrc[(size_t)t * DM + j]);   // B[e][r][j]
    } else {
        const int p = b - 3072;
        const int e = p >> 4, r = p & 15;
        for (int d = t; d < DM; d += 256)
            At[(size_t)p * DM + d] = f2bf(Asrc[e * (DM * NR) + d * NR + r]);
    }
}

// ---------------------------------------------------------------------------
// hall: Hfull = (x_bf16 @ At^T) * combine -> bf16 into Xext[:, 1024:1152]
//   tile 32 tokens x 128 cols, BK=64, XOR-swizzled LDS (2-way banks, free).
// ---------------------------------------------------------------------------
__global__ __launch_bounds__(256) void hall_kernel(unsigned short* Xext,
                                                   const unsigned short* __restrict__ At,
                                                   const float* __restrict__ combine) {
    __shared__ __align__(16) unsigned short lds[(32 + 128) * 64];  // A:4KB  B:16KB
    const int t = threadIdx.x;
    const int lane = t & 63;
    const int w = t >> 6;
    const int quad = lane >> 4;
    const int l15 = lane & 15;
    const int bm = blockIdx.x;

    const int srow = t >> 3;                     // 0..31
    const int seg  = (t & 7) ^ (srow & 7);       // XOR swizzle (global side)

    f32x4 acc[2][2] = {};
    const unsigned short* gA = Xext + (size_t)(bm * 32 + srow) * KX + seg * 8;

    for (int k0 = 0; k0 < DM; k0 += 64) {
        __syncthreads();
        gld16(gA + k0, (char*)lds + w * 1024);
        #pragma unroll
        for (int r = 0; r < 4; ++r) {
            const unsigned short* g = At + (size_t)(r * 32 + srow) * DM + k0 + seg * 8;
            gld16(g, (char*)lds + 4096 + r * 4096 + w * 1024);
        }
        __syncthreads();
        #pragma unroll
        for (int kk = 0; kk < 2; ++kk) {
            const int gs = kk * 4 + quad;
            const int sw = (gs ^ (l15 & 7)) * 8;
            bf16x8 a[2], bb[2];
            #pragma unroll
            for (int i = 0; i < 2; ++i)
                a[i] = *(const bf16x8*)&lds[(i * 16 + l15) * 64 + sw];
            #pragma unroll
            for (int jf = 0; jf < 2; ++jf)
                bb[jf] = *(const bf16x8*)&lds[2048 + (w * 32 + jf * 16 + l15) * 64 + sw];
            #pragma unroll
            for (int i = 0; i < 2; ++i)
                #pragma unroll
                for (int jf = 0; jf < 2; ++jf)
                    acc[i][jf] = __builtin_amdgcn_mfma_f32_16x16x32_bf16(a[i], bb[jf], acc[i][jf], 0, 0, 0);
        }
    }
    #pragma unroll
    for (int i = 0; i < 2; ++i)
        #pragma unroll
        for (int jf = 0; jf < 2; ++jf) {
            const int p = w * 32 + jf * 16 + l15;
            const int e = p >> 4;
            #pragma unroll
            for (int v = 0; v < 4; ++v) {
                const int n = bm * 32 + i * 16 + quad * 4 + v;
                const float val = acc[i][jf][v] * combine[n * NE + e];
                Xext[(size_t)n * KX + DM + p] = f2bf(val);
            }
        }
}

// ---------------------------------------------------------------------------
// mgemm: out[8192][1024] = Xext[8192][1152] @ WBext[1024][1152]^T + bias
//   128x128 tile, BK=128 (9 iters, 18 barrier drains), 64 KB LDS
//   (A bytes [0,32768) | B bytes [32768,65536) -- R4's NaN was ldsB at
//   +65536, past the end of LDS), XOR-swizzled K-segments, epilogue
//   LDS-transpose for coalesced dwordx4 stores.
// ---------------------------------------------------------------------------
__global__ __launch_bounds__(256, 2) void mgemm(const unsigned short* __restrict__ Xext,
                                                const unsigned short* __restrict__ WBext,
                                                const float* __restrict__ bias,
                                                float* __restrict__ out) {
    __shared__ __align__(16) unsigned short lds[32768];   // 64 KB: A 32KB | B 32KB
    const int t = threadIdx.x;
    const int lane = t & 63;
    const int w = t >> 6;
    const int quad = lane >> 4;
    const int l15 = lane & 15;

    const int bid = blockIdx.x;          // 512
    const int xcd = bid & 7;             // XCD x owns bm in [8x,8x+8) x all bn
    const int loc = bid >> 3;
    const int bm = xcd * 8 + (loc & 7);  // 0..63
    const int bn = loc >> 3;             // 0..7

    const int wm = (w & 1) * 64;
    const int wn = (w >> 1) * 64;

    f32x4 acc[4][4] = {};

    // Staging: inst c covers rows c*16 + w*4 + (lane>>4); row = 256 B (16 segs).
    // seg swizzle is c-independent because c*16 == 0 (mod 8).
    const int srow = w * 4 + (lane >> 4);            // 0..15 (row within 16-row chunk)
    const int seg  = (lane & 15) ^ (srow & 7);       // global-side XOR swizzle
    const unsigned short* gA = Xext  + (size_t)(bm * 128 + srow) * KX + seg * 8;
    const unsigned short* gB = WBext + (size_t)(bn * 128 + srow) * KX + seg * 8;
    char* ldsA = (char*)lds + w * 1024;              // + lane*16 applied by HW
    char* ldsB = (char*)lds + 32768 + w * 1024;      // FIX: B region at byte 32768

    for (int k0 = 0; k0 < KX; k0 += 128) {           // 9 iterations
        __syncthreads();
        #pragma unroll
        for (int c = 0; c < 8; ++c) {
            gld16(gA + (size_t)c * 16 * KX + k0, ldsA + c * 4096);
            gld16(gB + (size_t)c * 16 * KX + k0, ldsB + c * 4096);
        }
        __syncthreads();
        #pragma unroll
        for (int kk = 0; kk < 4; ++kk) {
            const int gs = kk * 4 + quad;
            const int sw = (gs ^ (l15 & 7)) * 8;     // XOR affects low3 only; bit3 of gs kept
            bf16x8 a[4], b[4];
            #pragma unroll
            for (int i = 0; i < 4; ++i)
                a[i] = *(const bf16x8*)&lds[(wm + i * 16 + l15) * 128 + sw];
            #pragma unroll
            for (int j = 0; j < 4; ++j)
                b[j] = *(const bf16x8*)&lds[16384 + (wn + j * 16 + l15) * 128 + sw];
            #pragma unroll
            for (int i = 0; i < 4; ++i)
                #pragma unroll
                for (int j = 0; j < 4; ++j)
                    acc[i][j] = __builtin_amdgcn_mfma_f32_16x16x32_bf16(a[i], b[j], acc[i][j], 0, 0, 0);
        }
    }

    // Epilogue: per-wave 64x64 LDS transpose (16 KB each, reuses main LDS)
    // -> each lane stores float4 runs, fully coalesced 256 B per row-group.
    __syncthreads();                     // all waves done reading A/B tiles
    float* lf = (float*)lds + w * 4096;  // wave-private 64x64 fp32
    #pragma unroll
    for (int j = 0; j < 4; ++j) {
        const float bv = bias[bn * 128 + wn + j * 16 + l15];
        #pragma unroll
        for (int i = 0; i < 4; ++i)
            #pragma unroll
            for (int v = 0; v < 4; ++v) {
                const int row_l = i * 16 + quad * 4 + v;
                const int col_s = (j * 16 + l15) ^ ((row_l & 1) << 4);  // 2-way banks
                lf[row_l * 64 + col_s] = acc[i][j][v] + bv;
            }
    }
    __builtin_amdgcn_s_waitcnt(0);       // drain LDS writes (wave-local visibility)
    #pragma unroll
    for (int r = 0; r < 16; ++r) {
        const int row_r = r * 4 + (lane >> 4);
        const int col4  = (lane & 15) * 4;
        const int col4s = col4 ^ ((row_r & 1) << 4);
        float4 vv = *(const float4*)&lf[row_r * 64 + col4s];
        *(float4*)&out[(size_t)(bm * 128 + wm + row_r) * DM + bn * 128 + wn + col4] = vv;
    }
}

// ---------------------------------------------------------------------------
extern "C" void kernel_launch(void* const* d_in, const int* in_sizes, int n_in,
                              void* d_out, int out_size, void* d_ws, size_t ws_size,
                              hipStream_t stream) {
    const float* x  = (const float*)d_in[0];   // [8192,1024]
    const float* Wg = (const float*)d_in[1];   // [8,1024]
    const float* A  = (const float*)d_in[2];   // [8,1024,16]
    const float* B  = (const float*)d_in[3];   // [8,16,1024]
    const float* Wb = (const float*)d_in[4];   // [1024,1024]
    const float* bb = (const float*)d_in[5];   // [1024]
    float* out = (float*)d_out;

    char* ws = (char*)d_ws;
    float*          combine = (float*)ws;                                   // 262144 B
    unsigned short* Xext    = (unsigned short*)(ws + 262144);               // 18874368 B
    unsigned short* WBext   = (unsigned short*)(ws + 262144 + 18874368);    // 2359296 B
    unsigned short* At      = (unsigned short*)(ws + 262144 + 18874368 + 2359296); // 262144 B

    hipLaunchKernelGGL(prep,        dim3(3200), dim3(256), 0, stream,
                       x, Wg, A, B, Wb, combine, Xext, WBext, At);
    hipLaunchKernelGGL(hall_kernel, dim3(256),  dim3(256), 0, stream, Xext, At, combine);
    hipLaunchKernelGGL(mgemm,       dim3(512),  dim3(256), 0, stream, Xext, WBext, bb, out);
}